// Round 8
// baseline (206.185 us; speedup 1.0000x reference)
//
#include <hip/hip_runtime.h>

#define NUM_CODES 1024
#define DIM 32
#define ROWS 131072      // 16384 * 8
#define DECAYF 0.99f
#define EPSF 1e-5f
#define CCOST 0.25f
#define SLAB 33792       // 32768 dw + 1024 counts
#define IBLK (SLAB / 256)  // 132
#define TILES_PER_CHUNK 16
#define DBIAS 256.0f     // distance bias: keeps acc strictly negative

typedef __attribute__((ext_vector_type(8))) short short8v;
typedef __attribute__((ext_vector_type(4))) float f32x4;

__device__ __forceinline__ unsigned short bf16_rne(float f) {
    unsigned u = __float_as_uint(f);
    unsigned r = u + 0x7FFFu + ((u >> 16) & 1u);
    return (unsigned short)(r >> 16);
}

// ---------------- K0: prep — bf16 hi/lo B tables + biased norms + sumf2 zero ----
// slot = tile*64 + lane; B-frag layout: col = lane&15 (code within tile),
// k = (lane>>4)*8 + j. nbias[k] = -0.5||e_k||^2 - DBIAS (acc stays negative).
__global__ __launch_bounds__(256) void k_prep(const float* __restrict__ emb,
                                              unsigned short* __restrict__ bhi,
                                              unsigned short* __restrict__ blo,
                                              float* __restrict__ nbias,
                                              float* __restrict__ sumf2) {
    int s = blockIdx.x * 256 + threadIdx.x;   // 0..4095
    if (s == 0) sumf2[0] = 0.0f;
    if (s < NUM_CODES) {
        const float4* e4 = (const float4*)(emb + s * DIM);
        float sum = 0.0f;
#pragma unroll
        for (int j = 0; j < 8; ++j) {
            float4 e = e4[j];
            sum += e.x * e.x + e.y * e.y + e.z * e.z + e.w * e.w;
        }
        nbias[s] = -0.5f * sum - DBIAS;
    }
    int l = s & 63, t = s >> 6;
    int code = t * 16 + (l & 15);
    int koff = (l >> 4) * 8;
    const float* src = emb + code * DIM + koff;
    float4 f0 = *(const float4*)(src);
    float4 f1 = *(const float4*)(src + 4);
    float fv[8] = {f0.x, f0.y, f0.z, f0.w, f1.x, f1.y, f1.z, f1.w};
    short8v h, lo;
#pragma unroll
    for (int j = 0; j < 8; ++j) {
        unsigned short hb = bf16_rne(fv[j]);
        float hf = __uint_as_float((unsigned)hb << 16);
        h[j]  = (short)hb;
        lo[j] = (short)bf16_rne(fv[j] - hf);
    }
    *(short8v*)(bhi + (size_t)s * 8) = h;
    *(short8v*)(blo + (size_t)s * 8) = lo;
}

// ---------------- K1: MFMA distance + argmin + quantized write ----------
// Block = 4 waves owning the SAME 64 rows (4 A-frags each); wave w scans tiles
// [w*16, w*16+16) with 1-tile register prefetch. Chunk winners (packed u32:
// truncated acc bits | code) combined in LDS -> final idx; then coalesced
// qout gather-write. acc = f.e - 0.5||e||^2 - 256 < 0 always => raw-bit u32
// min == argmin dist. Numerics identical to R7 (same MFMA order/truncation).
// C/D layout (m89-verified): col = lane&15, row = (lane>>4)*4 + reg.
__global__ __launch_bounds__(256) void k_argmin(const float* __restrict__ flat,
                                                const unsigned short* __restrict__ bhi_g,
                                                const unsigned short* __restrict__ blo_g,
                                                const float* __restrict__ nbias,
                                                const float* __restrict__ emb,
                                                int* __restrict__ idx_out,
                                                float* __restrict__ idxf_out,
                                                float* __restrict__ qout) {
    __shared__ unsigned win[4][64];
    __shared__ int kwin[64];
    const int lane = threadIdx.x & 63;
    const int wid  = threadIdx.x >> 6;       // chunk 0..3
    const int rowbase = blockIdx.x * 64;
    const int lr = lane & 15;   // A row / B,C col within frag
    const int lg = lane >> 4;   // k-group

    // load + hi/lo split A (4 row-frags, 64 rows)
    short8v ahi[4], alo[4];
#pragma unroll
    for (int rf = 0; rf < 4; ++rf) {
        const float* src = flat + (size_t)(rowbase + rf * 16 + lr) * DIM + lg * 8;
        float4 f0 = *(const float4*)src;
        float4 f1 = *(const float4*)(src + 4);
        float fv[8] = {f0.x, f0.y, f0.z, f0.w, f1.x, f1.y, f1.z, f1.w};
        short8v h, lo;
#pragma unroll
        for (int j = 0; j < 8; ++j) {
            unsigned short hb = bf16_rne(fv[j]);
            float hf = __uint_as_float((unsigned)hb << 16);
            h[j]  = (short)hb;
            lo[j] = (short)bf16_rne(fv[j] - hf);
        }
        ahi[rf] = h; alo[rf] = lo;
    }

    unsigned best[4][4];
#pragma unroll
    for (int rf = 0; rf < 4; ++rf)
#pragma unroll
        for (int rg = 0; rg < 4; ++rg) best[rf][rg] = 0xFFFFFFFFu;

    const int t0 = wid * TILES_PER_CHUNK;
    const short8v* bhp = (const short8v*)(bhi_g + ((size_t)t0 * 64 + lane) * 8);
    const short8v* blp = (const short8v*)(blo_g + ((size_t)t0 * 64 + lane) * 8);
    short8v bh = bhp[0];
    short8v bl = blp[0];
    float   nn = nbias[t0 * 16 + lr];

#pragma unroll
    for (int tt = 0; tt < TILES_PER_CHUNK; ++tt) {
        short8v bhc = bh, blc = bl;
        float nnc = nn;
        unsigned code = (unsigned)((t0 + tt) * 16 + lr);
        if (tt + 1 < TILES_PER_CHUNK) {          // 1-tile register prefetch
            bh = bhp[(tt + 1) * 64];
            bl = blp[(tt + 1) * 64];
            nn = nbias[(t0 + tt + 1) * 16 + lr];
        }
#pragma unroll
        for (int rf = 0; rf < 4; ++rf) {
            f32x4 acc = {nnc, nnc, nnc, nnc};
            acc = __builtin_amdgcn_mfma_f32_16x16x32_bf16(ahi[rf], bhc, acc, 0, 0, 0);
            acc = __builtin_amdgcn_mfma_f32_16x16x32_bf16(ahi[rf], blc, acc, 0, 0, 0);
            acc = __builtin_amdgcn_mfma_f32_16x16x32_bf16(alo[rf], bhc, acc, 0, 0, 0);
#pragma unroll
            for (int rg = 0; rg < 4; ++rg) {
                unsigned pb = (__float_as_uint(acc[rg]) & 0xFFFFFC00u) | code;
                best[rf][rg] = min(best[rf][rg], pb);
            }
        }
    }

    // u32-min reduce across the 16-lane group; stash per-wave winner in LDS
#pragma unroll
    for (int rf = 0; rf < 4; ++rf) {
#pragma unroll
        for (int rg = 0; rg < 4; ++rg) {
            unsigned b = best[rf][rg];
#pragma unroll
            for (int m = 1; m < 16; m <<= 1)
                b = min(b, (unsigned)__shfl_xor((int)b, m));
            if (lr == rg) win[wid][rf * 16 + lg * 4 + rg] = b;
        }
    }
    __syncthreads();

    if (threadIdx.x < 64) {
        unsigned pm = min(min(win[0][threadIdx.x], win[1][threadIdx.x]),
                          min(win[2][threadIdx.x], win[3][threadIdx.x]));
        int k = (int)(pm & 1023u);
        kwin[threadIdx.x] = k;
        idx_out[rowbase + threadIdx.x]  = k;
        idxf_out[rowbase + threadIdx.x] = (float)k;
    }
    __syncthreads();

    // quantized write: 8 threads per row, coalesced 128B per row, 2 passes
#pragma unroll
    for (int h = 0; h < 2; ++h) {
        int row = h * 32 + (threadIdx.x >> 3), seg = threadIdx.x & 7;
        int k = kwin[row];
        float4 e = *(const float4*)(emb + (size_t)k * DIM + seg * 4);
        *(float4*)(qout + (size_t)(rowbase + row) * DIM + seg * 4) = e;
    }
}

// ---------------- K2: stats only — LDS-accumulated counts/dw + sum(f^2) ---------
__global__ __launch_bounds__(256) void k_scatter(const float* __restrict__ flat,
                                                 const int* __restrict__ idx,
                                                 float* __restrict__ slabs,
                                                 float* __restrict__ sumf2,
                                                 int rows_per_block) {
    __shared__ float acc[SLAB];   // 132 KB
    __shared__ float red[256];
    const int tid = threadIdx.x;
    for (int i = tid; i < SLAB; i += 256) acc[i] = 0.0f;
    __syncthreads();

    const int row0 = blockIdx.x * rows_per_block;
    float sf = 0.0f;
    for (int rr = 0; rr < rows_per_block; rr += 256) {
        int r = row0 + rr + tid;
        int k = idx[r];
        const float4* f4 = (const float4*)(flat + (size_t)r * DIM);
        int kb = k * DIM;
#pragma unroll
        for (int j4 = 0; j4 < 8; ++j4) {
            float4 f = f4[j4];
            sf += f.x * f.x + f.y * f.y + f.z * f.z + f.w * f.w;
            int j = 4 * j4;
            // swizzled LDS layout: entry (k,j) lives at k*32 + ((j+k)&31)
            atomicAdd(&acc[kb + ((j + 0 + k) & 31)], f.x);
            atomicAdd(&acc[kb + ((j + 1 + k) & 31)], f.y);
            atomicAdd(&acc[kb + ((j + 2 + k) & 31)], f.z);
            atomicAdd(&acc[kb + ((j + 3 + k) & 31)], f.w);
        }
        atomicAdd(&acc[32768 + k], 1.0f);
    }
    __syncthreads();

    // flush LDS -> per-block slab (un-swizzle; coalesced global writes)
    float* slab = slabs + (size_t)blockIdx.x * SLAB;
    for (int i = tid; i < 32768; i += 256) {
        int k = i >> 5, j = i & 31;
        slab[i] = acc[(i & ~31) | ((j + k) & 31)];
    }
    for (int i = tid; i < NUM_CODES; i += 256) slab[32768 + i] = acc[32768 + i];

    red[tid] = sf;
    __syncthreads();
    for (int s = 128; s > 0; s >>= 1) {
        if (tid < s) red[tid] += red[tid + s];
        __syncthreads();
    }
    if (tid == 0) atomicAdd(sumf2, red[0]);
}

// ---------------- K2b: single-stage slab reduction ----------------
__global__ __launch_bounds__(256) void k_reduce(const float* __restrict__ slabs,
                                                float* __restrict__ dw_sum,
                                                float* __restrict__ counts_sum,
                                                int P) {
    int i = blockIdx.x * 256 + threadIdx.x;
    float s = 0.0f;
    for (int p = 0; p < P; ++p) s += slabs[(size_t)p * SLAB + i];
    if (i < 32768) dw_sum[i] = s;
    else           counts_sum[i - 32768] = s;
}

// ---------------- K3: finalize (single block, 1024 threads) ----------------
// loss via identity:
// sum||e-f||^2 = sum||f||^2 + sum_k c_k||e_k||^2 - 2 sum e_k . dw_k  (f64 accum)
__global__ __launch_bounds__(1024) void k_final(const float* __restrict__ ema_cs,
                                                const float* __restrict__ ema_w,
                                                const float* __restrict__ emb,
                                                const float* __restrict__ counts,
                                                const float* __restrict__ dw,
                                                const float* __restrict__ sumf2,
                                                float* __restrict__ out_loss,
                                                float* __restrict__ out_perp,
                                                float* __restrict__ out_emb,
                                                float* __restrict__ out_cs,
                                                float* __restrict__ out_ema_w) {
    int tid = threadIdx.x;
    __shared__ float s_cs[NUM_CODES];
    __shared__ float s_cnt[NUM_CODES];
    __shared__ float red[1024];
    __shared__ double redd[1024];

    float c = counts[tid];
    s_cnt[tid] = c;
    float pre = ema_cs[tid] * DECAYF + (1.0f - DECAYF) * c;

    red[tid] = pre;
    __syncthreads();
    for (int s = 512; s > 0; s >>= 1) {
        if (tid < s) red[tid] += red[tid + s];
        __syncthreads();
    }
    float n = red[0];
    __syncthreads();

    float ncs = (pre + EPSF) / (n + (float)NUM_CODES * EPSF) * n;
    s_cs[tid] = ncs;
    out_cs[tid] = ncs;

    float p = c / (float)ROWS;
    red[tid] = p * logf(p + 1e-10f);
    __syncthreads();
    for (int s = 512; s > 0; s >>= 1) {
        if (tid < s) red[tid] += red[tid + s];
        __syncthreads();
    }
    float nplogp = red[0];
    __syncthreads();

    // dw pass: EMA update, new embedding, and loss terms
    double lterm = 0.0;   // c_k e^2 - 2 e . dw, accumulated elementwise
    for (int i = tid; i < NUM_CODES * DIM; i += 1024) {
        int k = i >> 5;
        float dwv = dw[i];
        float e = emb[i];
        lterm += (double)e * ((double)e * (double)s_cnt[k] - 2.0 * (double)dwv);
        float w = ema_w[i] * DECAYF + (1.0f - DECAYF) * dwv;
        out_ema_w[i] = w;
        out_emb[i] = w / s_cs[k];
    }
    redd[tid] = lterm;
    __syncthreads();
    for (int s = 512; s > 0; s >>= 1) {
        if (tid < s) redd[tid] += redd[tid + s];
        __syncthreads();
    }
    if (tid == 0) {
        double lsum = (double)sumf2[0] + redd[0];
        out_loss[0] = (float)(CCOST * lsum / (double)((size_t)ROWS * DIM));
        out_perp[0] = expf(-nplogp);
    }
}

extern "C" void kernel_launch(void* const* d_in, const int* in_sizes, int n_in,
                              void* d_out, int out_size, void* d_ws, size_t ws_size,
                              hipStream_t stream) {
    const float* inputs    = (const float*)d_in[0];   // [16384,256]
    const float* embedding = (const float*)d_in[1];   // [1024,32]
    const float* ema_cs    = (const float*)d_in[2];   // [1024]
    const float* ema_w     = (const float*)d_in[3];   // [1024,32]

    // output layout (flat f32, return order)
    float* out        = (float*)d_out;
    float* out_loss   = out;                       // 1
    float* out_q      = out + 1;                   // 4194304
    float* out_perp   = out + 4194305;             // 1
    float* out_idxf   = out + 4194306;             // 131072
    float* out_emb    = out + 4325378;             // 32768
    float* out_cs     = out + 4358146;             // 1024
    float* out_ema_w  = out + 4359170;             // 32768

    // workspace layout (bytes)
    char* ws = (char*)d_ws;
    float* nbias      = (float*)(ws);                // 1024 f32   @ 0
    float* sumf2      = (float*)(ws + 4096);         // 1 f32      @ 4096
    int*   idx        = (int*)(ws + 8192);           // 131072 i32 @ 8192 .. 532480
    unsigned short* bhi_g = (unsigned short*)(ws + 532480);  // 64 KB .. 598016
    unsigned short* blo_g = (unsigned short*)(ws + 598016);  // 64 KB .. 663552
    float* dw_sum     = (float*)(ws + 663552);       // 32768 f32 .. 794624
    float* counts_sum = (float*)(ws + 794624);       // 1024 f32  .. 798720
    float* slabs      = (float*)(ws + 798720);       // P * 33792 f32

    size_t slab_off = 798720;
    size_t avail = (ws_size > slab_off) ? (ws_size - slab_off) : 0;
    int P = 16;
    if (avail >= (size_t)64 * SLAB * 4) P = 64;
    else if (avail >= (size_t)32 * SLAB * 4) P = 32;
    int rows_per_block = ROWS / P;

    k_prep   <<<16, 256, 0, stream>>>(embedding, bhi_g, blo_g, nbias, sumf2);
    k_argmin <<<ROWS / 64, 256, 0, stream>>>(inputs, bhi_g, blo_g, nbias, embedding,
                                             idx, out_idxf, out_q);
    k_scatter<<<P, 256, 0, stream>>>(inputs, idx, slabs, sumf2, rows_per_block);
    k_reduce <<<IBLK, 256, 0, stream>>>(slabs, dw_sum, counts_sum, P);
    k_final  <<<1, 1024, 0, stream>>>(ema_cs, ema_w, embedding, counts_sum, dw_sum,
                                      sumf2, out_loss, out_perp, out_emb, out_cs,
                                      out_ema_w);
}

// Round 9
// 133.975 us; speedup vs baseline: 1.5390x; 1.5390x over previous
//
#include <hip/hip_runtime.h>

#define NUM_CODES 1024
#define DIM 32
#define ROWS 131072      // 16384 * 8
#define DECAYF 0.99f
#define EPSF 1e-5f
#define CCOST 0.25f
#define SLAB 33792       // 32768 dw + 1024 counts
#define RGROUPS 8        // reduce stage-1 groups
#define IBLK (SLAB / 256)  // 132
#define TILES_PER_CHUNK 16
#define DBIAS 256.0f     // distance bias: keeps acc strictly negative

typedef __attribute__((ext_vector_type(8))) short short8v;
typedef __attribute__((ext_vector_type(4))) float f32x4;

__device__ __forceinline__ unsigned short bf16_rne(float f) {
    unsigned u = __float_as_uint(f);
    unsigned r = u + 0x7FFFu + ((u >> 16) & 1u);
    return (unsigned short)(r >> 16);
}

// ---------------- K0: prep — bf16 hi/lo B tables + biased norms + sumf2 zero ----
// slot = tile*64 + lane; B-frag layout: col = lane&15 (code within tile),
// k = (lane>>4)*8 + j. nbias[k] = -0.5||e_k||^2 - DBIAS (acc stays negative).
__global__ __launch_bounds__(256) void k_prep(const float* __restrict__ emb,
                                              unsigned short* __restrict__ bhi,
                                              unsigned short* __restrict__ blo,
                                              float* __restrict__ nbias,
                                              float* __restrict__ sumf2) {
    int s = blockIdx.x * 256 + threadIdx.x;   // 0..4095
    if (s == 0) sumf2[0] = 0.0f;
    if (s < NUM_CODES) {
        const float4* e4 = (const float4*)(emb + s * DIM);
        float sum = 0.0f;
#pragma unroll
        for (int j = 0; j < 8; ++j) {
            float4 e = e4[j];
            sum += e.x * e.x + e.y * e.y + e.z * e.z + e.w * e.w;
        }
        nbias[s] = -0.5f * sum - DBIAS;
    }
    int l = s & 63, t = s >> 6;
    int code = t * 16 + (l & 15);
    int koff = (l >> 4) * 8;
    const float* src = emb + code * DIM + koff;
    float4 f0 = *(const float4*)(src);
    float4 f1 = *(const float4*)(src + 4);
    float fv[8] = {f0.x, f0.y, f0.z, f0.w, f1.x, f1.y, f1.z, f1.w};
    short8v h, lo;
#pragma unroll
    for (int j = 0; j < 8; ++j) {
        unsigned short hb = bf16_rne(fv[j]);
        float hf = __uint_as_float((unsigned)hb << 16);
        h[j]  = (short)hb;
        lo[j] = (short)bf16_rne(fv[j] - hf);
    }
    *(short8v*)(bhi + (size_t)s * 8) = h;
    *(short8v*)(blo + (size_t)s * 8) = lo;
}

// ---------------- K1: MFMA distance + argmin + quantized write ----------
// Block = 4 waves owning the SAME 64 rows (4 A-frags each); wave w scans tiles
// [w*16, w*16+16) with 1-tile register prefetch. Chunk winners (packed u32:
// truncated acc bits | code) combined in LDS -> final idx; then coalesced
// qout gather-write. acc = f.e - 0.5||e||^2 - 256 < 0 always => raw-bit u32
// min == argmin dist. Numerics identical to R7 (same MFMA order/truncation).
// C/D layout (m89-verified): col = lane&15, row = (lane>>4)*4 + reg.
__global__ __launch_bounds__(256) void k_argmin(const float* __restrict__ flat,
                                                const unsigned short* __restrict__ bhi_g,
                                                const unsigned short* __restrict__ blo_g,
                                                const float* __restrict__ nbias,
                                                const float* __restrict__ emb,
                                                int* __restrict__ idx_out,
                                                float* __restrict__ idxf_out,
                                                float* __restrict__ qout) {
    __shared__ unsigned win[4][64];
    __shared__ int kwin[64];
    const int lane = threadIdx.x & 63;
    const int wid  = threadIdx.x >> 6;       // chunk 0..3
    const int rowbase = blockIdx.x * 64;
    const int lr = lane & 15;   // A row / B,C col within frag
    const int lg = lane >> 4;   // k-group

    // load + hi/lo split A (4 row-frags, 64 rows)
    short8v ahi[4], alo[4];
#pragma unroll
    for (int rf = 0; rf < 4; ++rf) {
        const float* src = flat + (size_t)(rowbase + rf * 16 + lr) * DIM + lg * 8;
        float4 f0 = *(const float4*)src;
        float4 f1 = *(const float4*)(src + 4);
        float fv[8] = {f0.x, f0.y, f0.z, f0.w, f1.x, f1.y, f1.z, f1.w};
        short8v h, lo;
#pragma unroll
        for (int j = 0; j < 8; ++j) {
            unsigned short hb = bf16_rne(fv[j]);
            float hf = __uint_as_float((unsigned)hb << 16);
            h[j]  = (short)hb;
            lo[j] = (short)bf16_rne(fv[j] - hf);
        }
        ahi[rf] = h; alo[rf] = lo;
    }

    unsigned best[4][4];
#pragma unroll
    for (int rf = 0; rf < 4; ++rf)
#pragma unroll
        for (int rg = 0; rg < 4; ++rg) best[rf][rg] = 0xFFFFFFFFu;

    const int t0 = wid * TILES_PER_CHUNK;
    const short8v* bhp = (const short8v*)(bhi_g + ((size_t)t0 * 64 + lane) * 8);
    const short8v* blp = (const short8v*)(blo_g + ((size_t)t0 * 64 + lane) * 8);
    short8v bh = bhp[0];
    short8v bl = blp[0];
    float   nn = nbias[t0 * 16 + lr];

#pragma unroll
    for (int tt = 0; tt < TILES_PER_CHUNK; ++tt) {
        short8v bhc = bh, blc = bl;
        float nnc = nn;
        unsigned code = (unsigned)((t0 + tt) * 16 + lr);
        if (tt + 1 < TILES_PER_CHUNK) {          // 1-tile register prefetch
            bh = bhp[(tt + 1) * 64];
            bl = blp[(tt + 1) * 64];
            nn = nbias[(t0 + tt + 1) * 16 + lr];
        }
#pragma unroll
        for (int rf = 0; rf < 4; ++rf) {
            f32x4 acc = {nnc, nnc, nnc, nnc};
            acc = __builtin_amdgcn_mfma_f32_16x16x32_bf16(ahi[rf], bhc, acc, 0, 0, 0);
            acc = __builtin_amdgcn_mfma_f32_16x16x32_bf16(ahi[rf], blc, acc, 0, 0, 0);
            acc = __builtin_amdgcn_mfma_f32_16x16x32_bf16(alo[rf], bhc, acc, 0, 0, 0);
#pragma unroll
            for (int rg = 0; rg < 4; ++rg) {
                unsigned pb = (__float_as_uint(acc[rg]) & 0xFFFFFC00u) | code;
                best[rf][rg] = min(best[rf][rg], pb);
            }
        }
    }

    // u32-min reduce across the 16-lane group; stash per-wave winner in LDS
#pragma unroll
    for (int rf = 0; rf < 4; ++rf) {
#pragma unroll
        for (int rg = 0; rg < 4; ++rg) {
            unsigned b = best[rf][rg];
#pragma unroll
            for (int m = 1; m < 16; m <<= 1)
                b = min(b, (unsigned)__shfl_xor((int)b, m));
            if (lr == rg) win[wid][rf * 16 + lg * 4 + rg] = b;
        }
    }
    __syncthreads();

    if (threadIdx.x < 64) {
        unsigned pm = min(min(win[0][threadIdx.x], win[1][threadIdx.x]),
                          min(win[2][threadIdx.x], win[3][threadIdx.x]));
        int k = (int)(pm & 1023u);
        kwin[threadIdx.x] = k;
        idx_out[rowbase + threadIdx.x]  = k;
        idxf_out[rowbase + threadIdx.x] = (float)k;
    }
    __syncthreads();

    // quantized write: 8 threads per row, coalesced 128B per row, 2 passes
#pragma unroll
    for (int h = 0; h < 2; ++h) {
        int row = h * 32 + (threadIdx.x >> 3), seg = threadIdx.x & 7;
        int k = kwin[row];
        float4 e = *(const float4*)(emb + (size_t)k * DIM + seg * 4);
        *(float4*)(qout + (size_t)(rowbase + row) * DIM + seg * 4) = e;
    }
}

// ---------------- K2: stats — LDS-accumulated counts/dw + sum(f^2) ---------
// 256 blocks (1/CU, 132 KB LDS) x 512 threads (8 waves): one row per thread.
__global__ __launch_bounds__(512) void k_scatter(const float* __restrict__ flat,
                                                 const int* __restrict__ idx,
                                                 float* __restrict__ slabs,
                                                 float* __restrict__ sumf2,
                                                 int rows_per_block) {
    __shared__ float acc[SLAB];   // 132 KB
    __shared__ float red[512];
    const int tid = threadIdx.x;
    for (int i = tid; i < SLAB; i += 512) acc[i] = 0.0f;
    __syncthreads();

    const int row0 = blockIdx.x * rows_per_block;
    float sf = 0.0f;
    for (int rr = 0; rr < rows_per_block; rr += 512) {
        int r = row0 + rr + tid;
        int k = idx[r];
        const float4* f4 = (const float4*)(flat + (size_t)r * DIM);
        int kb = k * DIM;
#pragma unroll
        for (int j4 = 0; j4 < 8; ++j4) {
            float4 f = f4[j4];
            sf += f.x * f.x + f.y * f.y + f.z * f.z + f.w * f.w;
            int j = 4 * j4;
            // swizzled LDS layout: entry (k,j) lives at k*32 + ((j+k)&31)
            atomicAdd(&acc[kb + ((j + 0 + k) & 31)], f.x);
            atomicAdd(&acc[kb + ((j + 1 + k) & 31)], f.y);
            atomicAdd(&acc[kb + ((j + 2 + k) & 31)], f.z);
            atomicAdd(&acc[kb + ((j + 3 + k) & 31)], f.w);
        }
        atomicAdd(&acc[32768 + k], 1.0f);
    }
    __syncthreads();

    // flush LDS -> per-block slab (un-swizzle; coalesced global writes)
    float* slab = slabs + (size_t)blockIdx.x * SLAB;
    for (int i = tid; i < 32768; i += 512) {
        int k = i >> 5, j = i & 31;
        slab[i] = acc[(i & ~31) | ((j + k) & 31)];
    }
    for (int i = tid; i < NUM_CODES; i += 512) slab[32768 + i] = acc[32768 + i];

    red[tid] = sf;
    __syncthreads();
    for (int s = 256; s > 0; s >>= 1) {
        if (tid < s) red[tid] += red[tid + s];
        __syncthreads();
    }
    if (tid == 0) atomicAdd(sumf2, red[0]);
}

// ---------------- K2b: two-stage slab reduction ----------------
__global__ __launch_bounds__(256) void k_reduce1(const float* __restrict__ slabs,
                                                 float* __restrict__ partial,
                                                 int pcount) {
    int g  = blockIdx.x / IBLK;
    int ib = blockIdx.x % IBLK;
    int i = ib * 256 + threadIdx.x;
    const float* base = slabs + (size_t)g * pcount * SLAB + i;
    float s = 0.0f;
#pragma unroll 4
    for (int p = 0; p < pcount; ++p) s += base[(size_t)p * SLAB];
    partial[(size_t)g * SLAB + i] = s;
}

__global__ __launch_bounds__(256) void k_reduce2(const float* __restrict__ partial,
                                                 float* __restrict__ dw_sum,
                                                 float* __restrict__ counts_sum) {
    int i = blockIdx.x * 256 + threadIdx.x;
    float s = 0.0f;
#pragma unroll
    for (int g = 0; g < RGROUPS; ++g) s += partial[(size_t)g * SLAB + i];
    if (i < 32768) dw_sum[i] = s;
    else           counts_sum[i - 32768] = s;
}

// ---------------- K3: finalize (single block, 1024 threads) ----------------
// loss via identity:
// sum||e-f||^2 = sum||f||^2 + sum_k c_k||e_k||^2 - 2 sum e_k . dw_k  (f64 accum)
__global__ __launch_bounds__(1024) void k_final(const float* __restrict__ ema_cs,
                                                const float* __restrict__ ema_w,
                                                const float* __restrict__ emb,
                                                const float* __restrict__ counts,
                                                const float* __restrict__ dw,
                                                const float* __restrict__ sumf2,
                                                float* __restrict__ out_loss,
                                                float* __restrict__ out_perp,
                                                float* __restrict__ out_emb,
                                                float* __restrict__ out_cs,
                                                float* __restrict__ out_ema_w) {
    int tid = threadIdx.x;
    __shared__ float s_cs[NUM_CODES];
    __shared__ float s_cnt[NUM_CODES];
    __shared__ float red[1024];
    __shared__ double redd[1024];

    float c = counts[tid];
    s_cnt[tid] = c;
    float pre = ema_cs[tid] * DECAYF + (1.0f - DECAYF) * c;

    red[tid] = pre;
    __syncthreads();
    for (int s = 512; s > 0; s >>= 1) {
        if (tid < s) red[tid] += red[tid + s];
        __syncthreads();
    }
    float n = red[0];
    __syncthreads();

    float ncs = (pre + EPSF) / (n + (float)NUM_CODES * EPSF) * n;
    s_cs[tid] = ncs;
    out_cs[tid] = ncs;

    float p = c / (float)ROWS;
    red[tid] = p * logf(p + 1e-10f);
    __syncthreads();
    for (int s = 512; s > 0; s >>= 1) {
        if (tid < s) red[tid] += red[tid + s];
        __syncthreads();
    }
    float nplogp = red[0];
    __syncthreads();

    // dw pass: EMA update, new embedding, and loss terms
    double lterm = 0.0;   // c_k e^2 - 2 e . dw, accumulated elementwise
    for (int i = tid; i < NUM_CODES * DIM; i += 1024) {
        int k = i >> 5;
        float dwv = dw[i];
        float e = emb[i];
        lterm += (double)e * ((double)e * (double)s_cnt[k] - 2.0 * (double)dwv);
        float w = ema_w[i] * DECAYF + (1.0f - DECAYF) * dwv;
        out_ema_w[i] = w;
        out_emb[i] = w / s_cs[k];
    }
    redd[tid] = lterm;
    __syncthreads();
    for (int s = 512; s > 0; s >>= 1) {
        if (tid < s) redd[tid] += redd[tid + s];
        __syncthreads();
    }
    if (tid == 0) {
        double lsum = (double)sumf2[0] + redd[0];
        out_loss[0] = (float)(CCOST * lsum / (double)((size_t)ROWS * DIM));
        out_perp[0] = expf(-nplogp);
    }
}

extern "C" void kernel_launch(void* const* d_in, const int* in_sizes, int n_in,
                              void* d_out, int out_size, void* d_ws, size_t ws_size,
                              hipStream_t stream) {
    const float* inputs    = (const float*)d_in[0];   // [16384,256]
    const float* embedding = (const float*)d_in[1];   // [1024,32]
    const float* ema_cs    = (const float*)d_in[2];   // [1024]
    const float* ema_w     = (const float*)d_in[3];   // [1024,32]

    // output layout (flat f32, return order)
    float* out        = (float*)d_out;
    float* out_loss   = out;                       // 1
    float* out_q      = out + 1;                   // 4194304
    float* out_perp   = out + 4194305;             // 1
    float* out_idxf   = out + 4194306;             // 131072
    float* out_emb    = out + 4325378;             // 32768
    float* out_cs     = out + 4358146;             // 1024
    float* out_ema_w  = out + 4359170;             // 32768

    // workspace layout (bytes)
    char* ws = (char*)d_ws;
    float* nbias      = (float*)(ws);                // 1024 f32   @ 0
    float* sumf2      = (float*)(ws + 4096);         // 1 f32      @ 4096
    int*   idx        = (int*)(ws + 8192);           // 131072 i32 @ 8192 .. 532480
    unsigned short* bhi_g = (unsigned short*)(ws + 532480);  // 64 KB .. 598016
    unsigned short* blo_g = (unsigned short*)(ws + 598016);  // 64 KB .. 663552
    float* dw_sum     = (float*)(ws + 663552);       // 32768 f32 .. 794624
    float* counts_sum = (float*)(ws + 794624);       // 1024 f32  .. 798720
    float* partial    = (float*)(ws + 798720);       // 8*33792 f32 .. 1880064
    float* slabs      = (float*)(ws + 1880064);      // P * 33792 f32

    size_t slab_off = 1880064;
    size_t avail = (ws_size > slab_off) ? (ws_size - slab_off) : 0;
    int P = 32;   // minimum fallback
    if (avail >= (size_t)256 * SLAB * 4) P = 256;
    else if (avail >= (size_t)128 * SLAB * 4) P = 128;
    else if (avail >= (size_t)64 * SLAB * 4) P = 64;
    int rows_per_block = ROWS / P;

    k_prep   <<<16, 256, 0, stream>>>(embedding, bhi_g, blo_g, nbias, sumf2);
    k_argmin <<<ROWS / 64, 256, 0, stream>>>(inputs, bhi_g, blo_g, nbias, embedding,
                                             idx, out_idxf, out_q);
    k_scatter<<<P, 512, 0, stream>>>(inputs, idx, slabs, sumf2, rows_per_block);
    k_reduce1<<<RGROUPS * IBLK, 256, 0, stream>>>(slabs, partial, P / RGROUPS);
    k_reduce2<<<IBLK, 256, 0, stream>>>(partial, dw_sum, counts_sum);
    k_final  <<<1, 1024, 0, stream>>>(ema_cs, ema_w, embedding, counts_sum, dw_sum,
                                      sumf2, out_loss, out_perp, out_emb, out_cs,
                                      out_ema_w);
}

// Round 10
// 104.318 us; speedup vs baseline: 1.9765x; 1.2843x over previous
//
#include <hip/hip_runtime.h>

#define NUM_CODES 1024
#define DIM 32
#define ROWS 131072      // 16384 * 8
#define DECAYF 0.99f
#define EPSF 1e-5f
#define CCOST 0.25f
#define SLAB 33792       // 32768 dw + 1024 counts
#define RGROUPS 8        // reduce stage-1 groups
#define IBLK (SLAB / 256)  // 132
#define TILES_PER_CHUNK 16
#define DBIAS 256.0f     // distance bias: keeps acc strictly negative

typedef __attribute__((ext_vector_type(8))) short short8v;
typedef __attribute__((ext_vector_type(4))) float f32x4;

__device__ __forceinline__ unsigned short bf16_rne(float f) {
    unsigned u = __float_as_uint(f);
    unsigned r = u + 0x7FFFu + ((u >> 16) & 1u);
    return (unsigned short)(r >> 16);
}

// ---------------- K0: prep — bf16 hi/lo B tables + biased norms + sumf2 zero ----
// slot = tile*64 + lane; B-frag layout: col = lane&15 (code within tile),
// k = (lane>>4)*8 + j. nbias[k] = -0.5||e_k||^2 - DBIAS (acc stays negative).
__global__ __launch_bounds__(256) void k_prep(const float* __restrict__ emb,
                                              unsigned short* __restrict__ bhi,
                                              unsigned short* __restrict__ blo,
                                              float* __restrict__ nbias,
                                              float* __restrict__ sumf2) {
    int s = blockIdx.x * 256 + threadIdx.x;   // 0..4095
    if (s == 0) sumf2[0] = 0.0f;
    if (s < NUM_CODES) {
        const float4* e4 = (const float4*)(emb + s * DIM);
        float sum = 0.0f;
#pragma unroll
        for (int j = 0; j < 8; ++j) {
            float4 e = e4[j];
            sum += e.x * e.x + e.y * e.y + e.z * e.z + e.w * e.w;
        }
        nbias[s] = -0.5f * sum - DBIAS;
    }
    int l = s & 63, t = s >> 6;
    int code = t * 16 + (l & 15);
    int koff = (l >> 4) * 8;
    const float* src = emb + code * DIM + koff;
    float4 f0 = *(const float4*)(src);
    float4 f1 = *(const float4*)(src + 4);
    float fv[8] = {f0.x, f0.y, f0.z, f0.w, f1.x, f1.y, f1.z, f1.w};
    short8v h, lo;
#pragma unroll
    for (int j = 0; j < 8; ++j) {
        unsigned short hb = bf16_rne(fv[j]);
        float hf = __uint_as_float((unsigned)hb << 16);
        h[j]  = (short)hb;
        lo[j] = (short)bf16_rne(fv[j] - hf);
    }
    *(short8v*)(bhi + (size_t)s * 8) = h;
    *(short8v*)(blo + (size_t)s * 8) = lo;
}

// ---------------- K1: MFMA distance + argmin + quantized write (LDS-staged B) ----
// 1024-thread block (16 waves): wave = (rowgroup wrg = wave>>2) x (chunk c = wave&3).
// Block stages the ENTIRE bhi/blo table (128 KB) + nbias into LDS once; each
// wave scans its 16-tile chunk against its 64 rows (4 A-frags). Winners
// (packed u32: truncated acc bits | code) combined across chunks in LDS.
// acc = f.e - 0.5||e||^2 - 256 < 0 always => raw-bit u32 min == argmin dist.
// Numerics identical to R7/R9 (same MFMA order/truncation) => same absmax.
// C/D layout (m89-verified): col = lane&15, row = (lane>>4)*4 + reg.
__global__ __launch_bounds__(1024) void k_argmin(const float* __restrict__ flat,
                                                 const unsigned short* __restrict__ bhi_g,
                                                 const unsigned short* __restrict__ blo_g,
                                                 const float* __restrict__ nbias,
                                                 const float* __restrict__ emb,
                                                 int* __restrict__ idx_out,
                                                 float* __restrict__ idxf_out,
                                                 float* __restrict__ qout) {
    __shared__ short8v s_bh[4096];     // 64 KB
    __shared__ short8v s_bl[4096];     // 64 KB
    __shared__ float   s_nb[NUM_CODES];   // 4 KB
    __shared__ unsigned s_win[4][256]; // 4 KB
    __shared__ int     s_kwin[256];    // 1 KB

    const int tid  = threadIdx.x;
    const int lane = tid & 63;
    const int wave = tid >> 6;        // 0..15
    const int c    = wave & 3;        // chunk
    const int wrg  = wave >> 2;       // rowgroup
    const int blockbase = blockIdx.x * 256;
    const int rowbase   = blockbase + wrg * 64;
    const int lr = lane & 15;   // A row / B,C col within frag
    const int lg = lane >> 4;   // k-group

    // ---- stage B tables + nbias into LDS (whole block cooperates) ----
    {
        const short8v* gh = (const short8v*)bhi_g;
        const short8v* gl = (const short8v*)blo_g;
#pragma unroll
        for (int i = 0; i < 4; ++i) {
            s_bh[i * 1024 + tid] = gh[i * 1024 + tid];
            s_bl[i * 1024 + tid] = gl[i * 1024 + tid];
        }
        if (tid < NUM_CODES) s_nb[tid] = nbias[tid];
    }

    // ---- load + hi/lo split A (4 row-frags = 64 rows per wave) ----
    short8v ahi[4], alo[4];
#pragma unroll
    for (int rf = 0; rf < 4; ++rf) {
        const float* src = flat + (size_t)(rowbase + rf * 16 + lr) * DIM + lg * 8;
        float4 f0 = *(const float4*)src;
        float4 f1 = *(const float4*)(src + 4);
        float fv[8] = {f0.x, f0.y, f0.z, f0.w, f1.x, f1.y, f1.z, f1.w};
        short8v h, lo;
#pragma unroll
        for (int j = 0; j < 8; ++j) {
            unsigned short hb = bf16_rne(fv[j]);
            float hf = __uint_as_float((unsigned)hb << 16);
            h[j]  = (short)hb;
            lo[j] = (short)bf16_rne(fv[j] - hf);
        }
        ahi[rf] = h; alo[rf] = lo;
    }

    unsigned best[4][4];
#pragma unroll
    for (int rf = 0; rf < 4; ++rf)
#pragma unroll
        for (int q = 0; q < 4; ++q) best[rf][q] = 0xFFFFFFFFu;

    __syncthreads();   // B tables ready

    const int t0 = c * TILES_PER_CHUNK;
#pragma unroll 2
    for (int tt = 0; tt < TILES_PER_CHUNK; ++tt) {
        const int t = t0 + tt;
        short8v bh = s_bh[t * 64 + lane];
        short8v bl = s_bl[t * 64 + lane];
        float nn   = s_nb[t * 16 + lr];
        unsigned code = (unsigned)(t * 16 + lr);
#pragma unroll
        for (int rf = 0; rf < 4; ++rf) {
            f32x4 acc = {nn, nn, nn, nn};
            acc = __builtin_amdgcn_mfma_f32_16x16x32_bf16(ahi[rf], bh, acc, 0, 0, 0);
            acc = __builtin_amdgcn_mfma_f32_16x16x32_bf16(ahi[rf], bl, acc, 0, 0, 0);
            acc = __builtin_amdgcn_mfma_f32_16x16x32_bf16(alo[rf], bh, acc, 0, 0, 0);
#pragma unroll
            for (int q = 0; q < 4; ++q) {
                unsigned pb = (__float_as_uint(acc[q]) & 0xFFFFFC00u) | code;
                best[rf][q] = min(best[rf][q], pb);
            }
        }
    }

    // u32-min reduce across the 16-lane group; stash per-(chunk,row) winner
#pragma unroll
    for (int rf = 0; rf < 4; ++rf) {
#pragma unroll
        for (int q = 0; q < 4; ++q) {
            unsigned b = best[rf][q];
#pragma unroll
            for (int m = 1; m < 16; m <<= 1)
                b = min(b, (unsigned)__shfl_xor((int)b, m));
            if (lr == q) s_win[c][wrg * 64 + rf * 16 + lg * 4 + q] = b;
        }
    }
    __syncthreads();

    if (tid < 256) {
        unsigned pm = min(min(s_win[0][tid], s_win[1][tid]),
                          min(s_win[2][tid], s_win[3][tid]));
        int k = (int)(pm & 1023u);
        s_kwin[tid] = k;
        idx_out[blockbase + tid]  = k;
        idxf_out[blockbase + tid] = (float)k;
    }
    __syncthreads();

    // quantized write: 8 threads per row, coalesced, 2 passes over 256 rows
#pragma unroll
    for (int h = 0; h < 2; ++h) {
        int i2  = h * 1024 + tid;
        int row = i2 >> 3, seg = i2 & 7;
        int k = s_kwin[row];
        float4 e = *(const float4*)(emb + (size_t)k * DIM + seg * 4);
        *(float4*)(qout + (size_t)(blockbase + row) * DIM + seg * 4) = e;
    }
}

// ---------------- K2: stats — LDS-accumulated counts/dw + sum(f^2) ---------
// 256 blocks (1/CU, 132 KB LDS) x 512 threads (8 waves): one row per thread.
__global__ __launch_bounds__(512) void k_scatter(const float* __restrict__ flat,
                                                 const int* __restrict__ idx,
                                                 float* __restrict__ slabs,
                                                 float* __restrict__ sumf2,
                                                 int rows_per_block) {
    __shared__ float acc[SLAB];   // 132 KB
    __shared__ float red[512];
    const int tid = threadIdx.x;
    for (int i = tid; i < SLAB; i += 512) acc[i] = 0.0f;
    __syncthreads();

    const int row0 = blockIdx.x * rows_per_block;
    float sf = 0.0f;
    for (int rr = 0; rr < rows_per_block; rr += 512) {
        int r = row0 + rr + tid;
        int k = idx[r];
        const float4* f4 = (const float4*)(flat + (size_t)r * DIM);
        int kb = k * DIM;
#pragma unroll
        for (int j4 = 0; j4 < 8; ++j4) {
            float4 f = f4[j4];
            sf += f.x * f.x + f.y * f.y + f.z * f.z + f.w * f.w;
            int j = 4 * j4;
            // swizzled LDS layout: entry (k,j) lives at k*32 + ((j+k)&31)
            atomicAdd(&acc[kb + ((j + 0 + k) & 31)], f.x);
            atomicAdd(&acc[kb + ((j + 1 + k) & 31)], f.y);
            atomicAdd(&acc[kb + ((j + 2 + k) & 31)], f.z);
            atomicAdd(&acc[kb + ((j + 3 + k) & 31)], f.w);
        }
        atomicAdd(&acc[32768 + k], 1.0f);
    }
    __syncthreads();

    // flush LDS -> per-block slab (un-swizzle; coalesced global writes)
    float* slab = slabs + (size_t)blockIdx.x * SLAB;
    for (int i = tid; i < 32768; i += 512) {
        int k = i >> 5, j = i & 31;
        slab[i] = acc[(i & ~31) | ((j + k) & 31)];
    }
    for (int i = tid; i < NUM_CODES; i += 512) slab[32768 + i] = acc[32768 + i];

    red[tid] = sf;
    __syncthreads();
    for (int s = 256; s > 0; s >>= 1) {
        if (tid < s) red[tid] += red[tid + s];
        __syncthreads();
    }
    if (tid == 0) atomicAdd(sumf2, red[0]);
}

// ---------------- K2b: two-stage slab reduction ----------------
__global__ __launch_bounds__(256) void k_reduce1(const float* __restrict__ slabs,
                                                 float* __restrict__ partial,
                                                 int pcount) {
    int g  = blockIdx.x / IBLK;
    int ib = blockIdx.x % IBLK;
    int i = ib * 256 + threadIdx.x;
    const float* base = slabs + (size_t)g * pcount * SLAB + i;
    float s = 0.0f;
#pragma unroll 4
    for (int p = 0; p < pcount; ++p) s += base[(size_t)p * SLAB];
    partial[(size_t)g * SLAB + i] = s;
}

__global__ __launch_bounds__(256) void k_reduce2(const float* __restrict__ partial,
                                                 float* __restrict__ dw_sum,
                                                 float* __restrict__ counts_sum) {
    int i = blockIdx.x * 256 + threadIdx.x;
    float s = 0.0f;
#pragma unroll
    for (int g = 0; g < RGROUPS; ++g) s += partial[(size_t)g * SLAB + i];
    if (i < 32768) dw_sum[i] = s;
    else           counts_sum[i - 32768] = s;
}

// ---------------- K3: finalize (single block, 1024 threads) ----------------
// loss via identity:
// sum||e-f||^2 = sum||f||^2 + sum_k c_k||e_k||^2 - 2 sum e_k . dw_k  (f64 accum)
__global__ __launch_bounds__(1024) void k_final(const float* __restrict__ ema_cs,
                                                const float* __restrict__ ema_w,
                                                const float* __restrict__ emb,
                                                const float* __restrict__ counts,
                                                const float* __restrict__ dw,
                                                const float* __restrict__ sumf2,
                                                float* __restrict__ out_loss,
                                                float* __restrict__ out_perp,
                                                float* __restrict__ out_emb,
                                                float* __restrict__ out_cs,
                                                float* __restrict__ out_ema_w) {
    int tid = threadIdx.x;
    __shared__ float s_cs[NUM_CODES];
    __shared__ float s_cnt[NUM_CODES];
    __shared__ float red[1024];
    __shared__ double redd[1024];

    float c = counts[tid];
    s_cnt[tid] = c;
    float pre = ema_cs[tid] * DECAYF + (1.0f - DECAYF) * c;

    red[tid] = pre;
    __syncthreads();
    for (int s = 512; s > 0; s >>= 1) {
        if (tid < s) red[tid] += red[tid + s];
        __syncthreads();
    }
    float n = red[0];
    __syncthreads();

    float ncs = (pre + EPSF) / (n + (float)NUM_CODES * EPSF) * n;
    s_cs[tid] = ncs;
    out_cs[tid] = ncs;

    float p = c / (float)ROWS;
    red[tid] = p * logf(p + 1e-10f);
    __syncthreads();
    for (int s = 512; s > 0; s >>= 1) {
        if (tid < s) red[tid] += red[tid + s];
        __syncthreads();
    }
    float nplogp = red[0];
    __syncthreads();

    // dw pass: EMA update, new embedding, and loss terms
    double lterm = 0.0;   // c_k e^2 - 2 e . dw, accumulated elementwise
    for (int i = tid; i < NUM_CODES * DIM; i += 1024) {
        int k = i >> 5;
        float dwv = dw[i];
        float e = emb[i];
        lterm += (double)e * ((double)e * (double)s_cnt[k] - 2.0 * (double)dwv);
        float w = ema_w[i] * DECAYF + (1.0f - DECAYF) * dwv;
        out_ema_w[i] = w;
        out_emb[i] = w / s_cs[k];
    }
    redd[tid] = lterm;
    __syncthreads();
    for (int s = 512; s > 0; s >>= 1) {
        if (tid < s) redd[tid] += redd[tid + s];
        __syncthreads();
    }
    if (tid == 0) {
        double lsum = (double)sumf2[0] + redd[0];
        out_loss[0] = (float)(CCOST * lsum / (double)((size_t)ROWS * DIM));
        out_perp[0] = expf(-nplogp);
    }
}

extern "C" void kernel_launch(void* const* d_in, const int* in_sizes, int n_in,
                              void* d_out, int out_size, void* d_ws, size_t ws_size,
                              hipStream_t stream) {
    const float* inputs    = (const float*)d_in[0];   // [16384,256]
    const float* embedding = (const float*)d_in[1];   // [1024,32]
    const float* ema_cs    = (const float*)d_in[2];   // [1024]
    const float* ema_w     = (const float*)d_in[3];   // [1024,32]

    // output layout (flat f32, return order)
    float* out        = (float*)d_out;
    float* out_loss   = out;                       // 1
    float* out_q      = out + 1;                   // 4194304
    float* out_perp   = out + 4194305;             // 1
    float* out_idxf   = out + 4194306;             // 131072
    float* out_emb    = out + 4325378;             // 32768
    float* out_cs     = out + 4358146;             // 1024
    float* out_ema_w  = out + 4359170;             // 32768

    // workspace layout (bytes)
    char* ws = (char*)d_ws;
    float* nbias      = (float*)(ws);                // 1024 f32   @ 0
    float* sumf2      = (float*)(ws + 4096);         // 1 f32      @ 4096
    int*   idx        = (int*)(ws + 8192);           // 131072 i32 @ 8192 .. 532480
    unsigned short* bhi_g = (unsigned short*)(ws + 532480);  // 64 KB .. 598016
    unsigned short* blo_g = (unsigned short*)(ws + 598016);  // 64 KB .. 663552
    float* dw_sum     = (float*)(ws + 663552);       // 32768 f32 .. 794624
    float* counts_sum = (float*)(ws + 794624);       // 1024 f32  .. 798720
    float* partial    = (float*)(ws + 798720);       // 8*33792 f32 .. 1880064
    float* slabs      = (float*)(ws + 1880064);      // P * 33792 f32

    size_t slab_off = 1880064;
    size_t avail = (ws_size > slab_off) ? (ws_size - slab_off) : 0;
    int P = 32;   // minimum fallback
    if (avail >= (size_t)256 * SLAB * 4) P = 256;
    else if (avail >= (size_t)128 * SLAB * 4) P = 128;
    else if (avail >= (size_t)64 * SLAB * 4) P = 64;
    int rows_per_block = ROWS / P;

    k_prep   <<<16, 256, 0, stream>>>(embedding, bhi_g, blo_g, nbias, sumf2);
    k_argmin <<<ROWS / 256, 1024, 0, stream>>>(inputs, bhi_g, blo_g, nbias, embedding,
                                               idx, out_idxf, out_q);
    k_scatter<<<P, 512, 0, stream>>>(inputs, idx, slabs, sumf2, rows_per_block);
    k_reduce1<<<RGROUPS * IBLK, 256, 0, stream>>>(slabs, partial, P / RGROUPS);
    k_reduce2<<<IBLK, 256, 0, stream>>>(partial, dw_sum, counts_sum);
    k_final  <<<1, 1024, 0, stream>>>(ema_cs, ema_w, embedding, counts_sum, dw_sum,
                                      sumf2, out_loss, out_perp, out_emb, out_cs,
                                      out_ema_w);
}